// Round 1
// baseline (378.111 us; speedup 1.0000x reference)
//
#include <hip/hip_runtime.h>
#include <hip/hip_bf16.h>

constexpr int IN_CH  = 128;
constexpr int HID_CH = 128;
constexpr int OUT_CH = 64;

// ---------------- CSR build ----------------

__global__ void k_count(const int* __restrict__ dst, int* __restrict__ cnt, int E) {
  int e = blockIdx.x * blockDim.x + threadIdx.x;
  if (e < E) atomicAdd(&cnt[dst[e]], 1);
}

__global__ void k_dinv(const int* __restrict__ cnt, float* __restrict__ dinv, int N) {
  int n = blockIdx.x * blockDim.x + threadIdx.x;
  if (n < N) dinv[n] = rsqrtf((float)cnt[n] + 1.0f);  // +1 self loop
}

__global__ __launch_bounds__(1024) void k_scan(const int* __restrict__ cnt,
                                               int* __restrict__ rowptr, int N) {
  __shared__ int sums[1024];
  int t = threadIdx.x;
  int per = (N + 1023) >> 10;
  int beg = t * per, end = min(beg + per, N);
  int s = 0;
  for (int i = beg; i < end; ++i) s += cnt[i];
  sums[t] = s;
  __syncthreads();
  for (int off = 1; off < 1024; off <<= 1) {
    int add = (t >= off) ? sums[t - off] : 0;
    __syncthreads();
    sums[t] += add;
    __syncthreads();
  }
  int run = (t == 0) ? 0 : sums[t - 1];
  for (int i = beg; i < end; ++i) { rowptr[i] = run; run += cnt[i]; }
  if (t == 1023) rowptr[N] = run;
}

__global__ void k_fill(const int* __restrict__ src, const int* __restrict__ dst,
                       const int* __restrict__ rowptr, int* __restrict__ cursor,
                       const float* __restrict__ dinv,
                       int* __restrict__ col, float* __restrict__ wsrc, int E) {
  int e = blockIdx.x * blockDim.x + threadIdx.x;
  if (e >= E) return;
  int d = dst[e], s = src[e];
  int p = rowptr[d] + atomicAdd(&cursor[d], 1);
  col[p]  = s;
  wsrc[p] = dinv[s];
}

// ---------------- dense GEMM (vector fp32; no fp32 MFMA on CDNA4) ----------------
// Y[N,OUT] = X[N,IN] @ W[IN,OUT]

template <int IN, int OUT, int ROWS, int KT>
__global__ __launch_bounds__(256) void k_gemm(const float* __restrict__ X,
                                              const float* __restrict__ W,
                                              float* __restrict__ Y, int N) {
  constexpr int RG  = 256 / OUT;   // row groups per k-step
  constexpr int RPT = ROWS / RG;   // rows per thread
  __shared__ float Ws[KT][OUT];
  __shared__ float Xs[ROWS][KT];
  int t = threadIdx.x;
  int row0 = blockIdx.x * ROWS;
  int c = t % OUT, rg = t / OUT;
  float acc[RPT] = {};
  for (int kb = 0; kb < IN; kb += KT) {
    for (int i = t; i < KT * OUT; i += 256)
      Ws[i / OUT][i % OUT] = W[(size_t)(kb + i / OUT) * OUT + (i % OUT)];
    for (int i = t; i < ROWS * KT; i += 256) {
      int r = row0 + i / KT;
      Xs[i / KT][i % KT] = (r < N) ? X[(size_t)r * IN + kb + (i % KT)] : 0.f;
    }
    __syncthreads();
#pragma unroll
    for (int k = 0; k < KT; ++k) {
      float w = Ws[k][c];
#pragma unroll
      for (int j = 0; j < RPT; ++j)
        acc[j] += Xs[rg + j * RG][k] * w;
    }
    __syncthreads();
  }
#pragma unroll
  for (int j = 0; j < RPT; ++j) {
    int r = row0 + rg + j * RG;
    if (r < N) Y[(size_t)r * OUT + c] = acc[j];
  }
}

// ---------------- normalized aggregation (gather-only SpMM row) ----------------
// Out[n,c] = act( dinv[n] * ( H[n,c]*dinv[n] + sum_e H[col,c]*dinv[col] ) + bias[c] )

template <int C, bool RELU>
__global__ __launch_bounds__(C) void k_agg(const float* __restrict__ H,
                                           const int* __restrict__ rowptr,
                                           const int* __restrict__ col,
                                           const float* __restrict__ wsrc,
                                           const float* __restrict__ dinv,
                                           const float* __restrict__ bias,
                                           float* __restrict__ Out, int N) {
  int n = blockIdx.x;
  int c = threadIdx.x;
  float dn = dinv[n];
  int p = rowptr[n], pend = rowptr[n + 1];
  float acc = H[(size_t)n * C + c] * dn;     // self loop (× dn again below)
  int   s_nxt = 0;
  float w_nxt = 0.f;
  if (p < pend) { s_nxt = col[p]; w_nxt = wsrc[p]; }
  while (p < pend) {
    int s = s_nxt; float w = w_nxt;
    ++p;
    if (p < pend) { s_nxt = col[p]; w_nxt = wsrc[p]; }  // prefetch next edge
    acc += H[(size_t)s * C + c] * w;
  }
  float v = dn * acc + bias[c];
  if (RELU) v = fmaxf(v, 0.f);
  Out[(size_t)n * C + c] = v;
}

// ---------------- decode: logits[i] = dot(z[a[i]], z[b[i]]) ----------------

__global__ __launch_bounds__(256) void k_decode(const float* __restrict__ Z,
                                                const int* __restrict__ ia,
                                                const int* __restrict__ ib,
                                                float* __restrict__ out, int L) {
  int lane = threadIdx.x & 63;
  int i = (blockIdx.x * blockDim.x + threadIdx.x) >> 6;  // one wave per pair
  if (i >= L) return;
  int na = ia[i], nb = ib[i];
  float p = Z[(size_t)na * OUT_CH + lane] * Z[(size_t)nb * OUT_CH + lane];
#pragma unroll
  for (int off = 32; off; off >>= 1) p += __shfl_xor(p, off);
  if (lane == 0) out[i] = p;
}

extern "C" void kernel_launch(void* const* d_in, const int* in_sizes, int n_in,
                              void* d_out, int out_size, void* d_ws, size_t ws_size,
                              hipStream_t stream) {
  const float* x   = (const float*)d_in[0];
  const int*   ei  = (const int*)d_in[1];
  const int*   eli = (const int*)d_in[2];
  const float* W1  = (const float*)d_in[3];
  const float* b1  = (const float*)d_in[4];
  const float* W2  = (const float*)d_in[5];
  const float* b2  = (const float*)d_in[6];
  float* logits = (float*)d_out;

  int N = in_sizes[0] / IN_CH;
  int E = in_sizes[1] / 2;
  int L = in_sizes[2] / 2;
  const int* src = ei;
  const int* dst = ei + E;
  const int* la  = eli;
  const int* lb  = eli + L;

  char* ws = (char*)d_ws;
  size_t off = 0;
  auto alloc = [&](size_t bytes) {
    void* p = ws + off;
    off = (off + bytes + 255) & ~(size_t)255;
    return p;
  };
  int*   cnt    = (int*)alloc((size_t)N * 4);
  int*   cursor = (int*)alloc((size_t)N * 4);
  int*   rowptr = (int*)alloc((size_t)(N + 1) * 4);
  float* dinv   = (float*)alloc((size_t)N * 4);
  int*   col    = (int*)alloc((size_t)E * 4);
  float* wsrc   = (float*)alloc((size_t)E * 4);
  float* h      = (float*)alloc((size_t)N * HID_CH * 4);
  float* hr     = (float*)alloc((size_t)N * HID_CH * 4);
  float* h2     = (float*)alloc((size_t)N * OUT_CH * 4);
  float* z      = (float*)alloc((size_t)N * OUT_CH * 4);

  // atomics + cursors must start at zero EVERY call (harness doesn't re-poison)
  hipMemsetAsync(cnt, 0, (size_t)N * 4, stream);
  hipMemsetAsync(cursor, 0, (size_t)N * 4, stream);

  const int TB = 256;
  k_count<<<(E + TB - 1) / TB, TB, 0, stream>>>(dst, cnt, E);
  k_dinv <<<(N + TB - 1) / TB, TB, 0, stream>>>(cnt, dinv, N);
  k_scan <<<1, 1024, 0, stream>>>(cnt, rowptr, N);
  k_fill <<<(E + TB - 1) / TB, TB, 0, stream>>>(src, dst, rowptr, cursor, dinv, col, wsrc, E);

  // layer 1: h = x@W1 ; hr = relu(norm-agg(h) + b1)
  k_gemm<IN_CH, HID_CH, 32, 32><<<(N + 31) / 32, 256, 0, stream>>>(x, W1, h, N);
  k_agg<HID_CH, true><<<N, HID_CH, 0, stream>>>(h, rowptr, col, wsrc, dinv, b1, hr, N);

  // layer 2: h2 = hr@W2 ; z = norm-agg(h2) + b2
  k_gemm<HID_CH, OUT_CH, 32, 32><<<(N + 31) / 32, 256, 0, stream>>>(hr, W2, h2, N);
  k_agg<OUT_CH, false><<<N, OUT_CH, 0, stream>>>(h2, rowptr, col, wsrc, dinv, b2, z, N);

  // decode
  k_decode<<<((size_t)L * 64 + 255) / 256, 256, 0, stream>>>(z, la, lb, logits, L);
}

// Round 2
// 280.322 us; speedup vs baseline: 1.3488x; 1.3488x over previous
//
#include <hip/hip_runtime.h>
#include <hip/hip_bf16.h>

constexpr int IN_CH  = 128;
constexpr int HID_CH = 128;
constexpr int OUT_CH = 64;

// ---------------- CSR build ----------------

__global__ void k_count(const int* __restrict__ dst, int* __restrict__ cnt, int E) {
  int e = blockIdx.x * blockDim.x + threadIdx.x;
  if (e < E) atomicAdd(&cnt[dst[e]], 1);
}

__global__ void k_dinv(const int* __restrict__ cnt, float* __restrict__ dinv, int N) {
  int n = blockIdx.x * blockDim.x + threadIdx.x;
  if (n < N) dinv[n] = rsqrtf((float)cnt[n] + 1.0f);  // +1 self loop
}

__global__ __launch_bounds__(1024) void k_scan(const int* __restrict__ cnt,
                                               int* __restrict__ rowptr, int N) {
  __shared__ int sums[1024];
  int t = threadIdx.x;
  int per = (N + 1023) >> 10;
  int beg = t * per, end = min(beg + per, N);
  int s = 0;
  for (int i = beg; i < end; ++i) s += cnt[i];
  sums[t] = s;
  __syncthreads();
  for (int off = 1; off < 1024; off <<= 1) {
    int add = (t >= off) ? sums[t - off] : 0;
    __syncthreads();
    sums[t] += add;
    __syncthreads();
  }
  int run = (t == 0) ? 0 : sums[t - 1];
  for (int i = beg; i < end; ++i) { rowptr[i] = run; run += cnt[i]; }
  if (t == 1023) rowptr[N] = run;
}

__global__ void k_fill(const int* __restrict__ src, const int* __restrict__ dst,
                       const int* __restrict__ rowptr, int* __restrict__ cursor,
                       const float* __restrict__ dinv,
                       int* __restrict__ col, float* __restrict__ wsrc, int E) {
  int e = blockIdx.x * blockDim.x + threadIdx.x;
  if (e >= E) return;
  int d = dst[e], s = src[e];
  int p = rowptr[d] + atomicAdd(&cursor[d], 1);
  col[p]  = s;
  wsrc[p] = dinv[s];
}

// ---------------- dense GEMM, register-tiled 4x4 (vector fp32) ----------------
// Y[N,OUT] = X[N,IN] @ W[IN,OUT]
// Per k-step each thread: 2x ds_read_b128 + 16 FMA  (VALU-bound, not LDS-bound)

template <int IN, int OUT>
__global__ __launch_bounds__(256) void k_gemm(const float* __restrict__ X,
                                              const float* __restrict__ W,
                                              float* __restrict__ Y, int N) {
  constexpr int NC = OUT / 4;      // col-threads (32 or 16)
  constexpr int MR = 256 / NC;     // row-threads (8 or 16)
  constexpr int MT = MR * 4;       // row tile (32 or 64)
  constexpr int KT = 32;
  constexpr int XP = MT + 4;       // pad keeps 16B alignment of Xt rows
  __shared__ float Ws[KT][OUT];
  __shared__ float Xt[KT][XP];
  int t = threadIdx.x;
  int row0 = blockIdx.x * MT;
  int tc = t % NC, tr = t / NC;
  float acc[4][4] = {};
  for (int kb = 0; kb < IN; kb += KT) {
    for (int i = t * 4; i < KT * OUT; i += 1024) {
      int k = i / OUT, c = i % OUT;
      *(float4*)&Ws[k][c] = *(const float4*)&W[(size_t)(kb + k) * OUT + c];
    }
    for (int i = t * 4; i < MT * KT; i += 1024) {
      int r = i / KT, k = i % KT;
      int gr = row0 + r;
      float4 v = make_float4(0.f, 0.f, 0.f, 0.f);
      if (gr < N) v = *(const float4*)&X[(size_t)gr * IN + kb + k];
      Xt[k + 0][r] = v.x; Xt[k + 1][r] = v.y; Xt[k + 2][r] = v.z; Xt[k + 3][r] = v.w;
    }
    __syncthreads();
#pragma unroll
    for (int k = 0; k < KT; ++k) {
      float4 xv = *(const float4*)&Xt[k][4 * tr];
      float4 wv = *(const float4*)&Ws[k][4 * tc];
      float xa[4] = {xv.x, xv.y, xv.z, xv.w};
      float wa[4] = {wv.x, wv.y, wv.z, wv.w};
#pragma unroll
      for (int j = 0; j < 4; ++j)
#pragma unroll
        for (int i2 = 0; i2 < 4; ++i2)
          acc[j][i2] += xa[j] * wa[i2];
    }
    __syncthreads();
  }
#pragma unroll
  for (int j = 0; j < 4; ++j) {
    int r = row0 + 4 * tr + j;
    if (r < N)
      *(float4*)&Y[(size_t)r * OUT + 4 * tc] =
          make_float4(acc[j][0], acc[j][1], acc[j][2], acc[j][3]);
  }
}

// ---------------- normalized aggregation (gather-only SpMM row) ----------------
// Out[n,c] = act( dinv[n] * ( H[n,c]*dinv[n] + sum_e H[col,c]*dinv[col] ) + bias[c] )
// 8-deep edge pipeline: 8 independent gathers in flight per thread.

template <int C, bool RELU>
__global__ __launch_bounds__(256) void k_agg(const float* __restrict__ H,
                                             const int* __restrict__ rowptr,
                                             const int* __restrict__ col,
                                             const float* __restrict__ wsrc,
                                             const float* __restrict__ dinv,
                                             const float* __restrict__ bias,
                                             float* __restrict__ Out, int N) {
  constexpr int NPB = 256 / C;  // nodes per block
  int n = blockIdx.x * NPB + threadIdx.x / C;
  if (n >= N) return;
  int c = threadIdx.x % C;
  float dn = dinv[n];
  int p = rowptr[n], pend = rowptr[n + 1];
  float acc = H[(size_t)n * C + c] * dn;  // self loop (x dn again below)
  for (; p + 8 <= pend; p += 8) {
    int s[8]; float w[8], hv[8];
#pragma unroll
    for (int j = 0; j < 8; ++j) { s[j] = col[p + j]; w[j] = wsrc[p + j]; }
#pragma unroll
    for (int j = 0; j < 8; ++j) hv[j] = H[(size_t)s[j] * C + c];
#pragma unroll
    for (int j = 0; j < 8; ++j) acc += hv[j] * w[j];
  }
  for (; p < pend; ++p) acc += H[(size_t)col[p] * C + c] * wsrc[p];
  float v = dn * acc + bias[c];
  if (RELU) v = fmaxf(v, 0.f);
  Out[(size_t)n * C + c] = v;
}

// ---------------- decode: logits[i] = dot(z[a[i]], z[b[i]]) ----------------
// 16 lanes per pair, float4 loads (256 B per row gather in one instr class).

__global__ __launch_bounds__(256) void k_decode(const float4* __restrict__ Z4,
                                                const int* __restrict__ ia,
                                                const int* __restrict__ ib,
                                                float* __restrict__ out, int L) {
  int t = blockIdx.x * 256 + threadIdx.x;
  int i = t >> 4;  // pair index, 16 threads each
  if (i >= L) return;
  int e = t & 15;
  int a = ia[i], b = ib[i];
  float4 za = Z4[(size_t)a * (OUT_CH / 4) + e];
  float4 zb = Z4[(size_t)b * (OUT_CH / 4) + e];
  float p = za.x * zb.x + za.y * zb.y + za.z * zb.z + za.w * zb.w;
  p += __shfl_xor(p, 1);
  p += __shfl_xor(p, 2);
  p += __shfl_xor(p, 4);
  p += __shfl_xor(p, 8);
  if (e == 0) out[i] = p;
}

extern "C" void kernel_launch(void* const* d_in, const int* in_sizes, int n_in,
                              void* d_out, int out_size, void* d_ws, size_t ws_size,
                              hipStream_t stream) {
  const float* x   = (const float*)d_in[0];
  const int*   ei  = (const int*)d_in[1];
  const int*   eli = (const int*)d_in[2];
  const float* W1  = (const float*)d_in[3];
  const float* b1  = (const float*)d_in[4];
  const float* W2  = (const float*)d_in[5];
  const float* b2  = (const float*)d_in[6];
  float* logits = (float*)d_out;

  int N = in_sizes[0] / IN_CH;
  int E = in_sizes[1] / 2;
  int L = in_sizes[2] / 2;
  const int* src = ei;
  const int* dst = ei + E;
  const int* la  = eli;
  const int* lb  = eli + L;

  char* ws = (char*)d_ws;
  size_t off = 0;
  auto alloc = [&](size_t bytes) {
    void* p = ws + off;
    off = (off + bytes + 255) & ~(size_t)255;
    return p;
  };
  int*   cnt    = (int*)alloc((size_t)N * 4);
  int*   cursor = (int*)alloc((size_t)N * 4);
  int*   rowptr = (int*)alloc((size_t)(N + 1) * 4);
  float* dinv   = (float*)alloc((size_t)N * 4);
  int*   col    = (int*)alloc((size_t)E * 4);
  float* wsrc   = (float*)alloc((size_t)E * 4);
  float* h      = (float*)alloc((size_t)N * HID_CH * 4);
  float* hr     = (float*)alloc((size_t)N * HID_CH * 4);
  float* h2     = (float*)alloc((size_t)N * OUT_CH * 4);
  float* z      = (float*)alloc((size_t)N * OUT_CH * 4);

  // atomics + cursors must start at zero EVERY call (harness doesn't re-poison)
  hipMemsetAsync(cnt, 0, (size_t)N * 4, stream);
  hipMemsetAsync(cursor, 0, (size_t)N * 4, stream);

  const int TB = 256;
  k_count<<<(E + TB - 1) / TB, TB, 0, stream>>>(dst, cnt, E);
  k_dinv <<<(N + TB - 1) / TB, TB, 0, stream>>>(cnt, dinv, N);
  k_scan <<<1, 1024, 0, stream>>>(cnt, rowptr, N);
  k_fill <<<(E + TB - 1) / TB, TB, 0, stream>>>(src, dst, rowptr, cursor, dinv, col, wsrc, E);

  // layer 1: h = x@W1 ; hr = relu(norm-agg(h) + b1)
  k_gemm<IN_CH, HID_CH><<<(N + 31) / 32, 256, 0, stream>>>(x, W1, h, N);
  k_agg<HID_CH, true><<<(N + 1) / 2, 256, 0, stream>>>(h, rowptr, col, wsrc, dinv, b1, hr, N);

  // layer 2: h2 = hr@W2 ; z = norm-agg(h2) + b2
  k_gemm<HID_CH, OUT_CH><<<(N + 63) / 64, 256, 0, stream>>>(hr, W2, h2, N);
  k_agg<OUT_CH, false><<<(N + 3) / 4, 256, 0, stream>>>(h2, rowptr, col, wsrc, dinv, b2, z, N);

  // decode
  k_decode<<<((size_t)L * 16 + 255) / 256, 256, 0, stream>>>((const float4*)z, la, lb, logits, L);
}

// Round 3
// 221.594 us; speedup vs baseline: 1.7063x; 1.2650x over previous
//
#include <hip/hip_runtime.h>
#include <hip/hip_bf16.h>

constexpr int IN_CH  = 128;
constexpr int HID_CH = 128;
constexpr int OUT_CH = 64;
constexpr int SCAN_CHUNK = 1024;   // elements per scan block (256 thr x 4)

// ---------------- CSR build ----------------

__global__ void k_count(const int* __restrict__ dst, int* __restrict__ cnt, int E) {
  int e = (blockIdx.x * blockDim.x + threadIdx.x) * 4;
  if (e + 3 < E) {
    int4 v = *(const int4*)&dst[e];
    atomicAdd(&cnt[v.x], 1); atomicAdd(&cnt[v.y], 1);
    atomicAdd(&cnt[v.z], 1); atomicAdd(&cnt[v.w], 1);
  } else {
    for (int j = 0; j < 4 && e + j < E; ++j) atomicAdd(&cnt[dst[e + j]], 1);
  }
}

__global__ void k_dinv(const int* __restrict__ cnt, float* __restrict__ dinv, int N) {
  int n = blockIdx.x * blockDim.x + threadIdx.x;
  if (n < N) dinv[n] = rsqrtf((float)cnt[n] + 1.0f);  // +1 self loop
}

// 3-phase multi-block exclusive scan of cnt -> rowptr
__global__ __launch_bounds__(256) void k_scan_part(const int* __restrict__ cnt,
                                                   int* __restrict__ bsum, int N) {
  int t = threadIdx.x;
  int base = blockIdx.x * SCAN_CHUNK + t * 4;
  int s = 0;
  if (base + 3 < N) {
    int4 v = *(const int4*)&cnt[base];
    s = v.x + v.y + v.z + v.w;
  } else {
    for (int j = 0; j < 4; ++j) if (base + j < N) s += cnt[base + j];
  }
  __shared__ int red[256];
  red[t] = s; __syncthreads();
  for (int off = 128; off; off >>= 1) {
    if (t < off) red[t] += red[t + off];
    __syncthreads();
  }
  if (t == 0) bsum[blockIdx.x] = red[0];
}

__global__ __launch_bounds__(256) void k_scan_top(const int* __restrict__ bsum,
                                                  int* __restrict__ boff, int nblk) {
  int t = threadIdx.x;
  __shared__ int s[256];
  int v = (t < nblk) ? bsum[t] : 0;
  s[t] = v; __syncthreads();
  for (int off = 1; off < 256; off <<= 1) {
    int add = (t >= off) ? s[t - off] : 0;
    __syncthreads();
    s[t] += add;
    __syncthreads();
  }
  if (t < nblk) boff[t] = s[t] - v;  // exclusive
}

__global__ __launch_bounds__(256) void k_scan_fill(const int* __restrict__ cnt,
                                                   const int* __restrict__ boff,
                                                   int* __restrict__ rowptr, int N, int E) {
  int t = threadIdx.x;
  int base = blockIdx.x * SCAN_CHUNK + t * 4;
  int v[4] = {0, 0, 0, 0};
  if (base + 3 < N) {
    int4 q = *(const int4*)&cnt[base];
    v[0] = q.x; v[1] = q.y; v[2] = q.z; v[3] = q.w;
  } else {
    for (int j = 0; j < 4; ++j) if (base + j < N) v[j] = cnt[base + j];
  }
  int mysum = v[0] + v[1] + v[2] + v[3];
  __shared__ int s[256];
  s[t] = mysum; __syncthreads();
  for (int off = 1; off < 256; off <<= 1) {
    int add = (t >= off) ? s[t - off] : 0;
    __syncthreads();
    s[t] += add;
    __syncthreads();
  }
  int run = boff[blockIdx.x] + s[t] - mysum;  // exclusive prefix for my 4
  for (int j = 0; j < 4; ++j) {
    if (base + j < N) rowptr[base + j] = run;
    run += v[j];
  }
  if (blockIdx.x == 0 && t == 0) rowptr[N] = E;
}

__global__ void k_fill(const int* __restrict__ src, const int* __restrict__ dst,
                       const int* __restrict__ rowptr, int* __restrict__ cursor,
                       const float* __restrict__ dinv,
                       int* __restrict__ col, float* __restrict__ wsrc, int E) {
  int e0 = (blockIdx.x * blockDim.x + threadIdx.x) * 4;
  if (e0 >= E) return;
  int sv[4], dv[4];
  if (e0 + 3 < E) {
    *(int4*)sv = *(const int4*)&src[e0];
    *(int4*)dv = *(const int4*)&dst[e0];
    for (int j = 0; j < 4; ++j) {
      int p = rowptr[dv[j]] + atomicAdd(&cursor[dv[j]], 1);
      col[p]  = sv[j];
      wsrc[p] = dinv[sv[j]];
    }
  } else {
    for (int j = 0; j < 4 && e0 + j < E; ++j) {
      int d = dst[e0 + j], s = src[e0 + j];
      int p = rowptr[d] + atomicAdd(&cursor[d], 1);
      col[p]  = s;
      wsrc[p] = dinv[s];
    }
  }
}

// ---------------- dense GEMM, register-tiled 4x4 (vector fp32) ----------------
// Y[N,OUT] = X[N,IN] @ W[IN,OUT]

template <int IN, int OUT>
__global__ __launch_bounds__(256) void k_gemm(const float* __restrict__ X,
                                              const float* __restrict__ W,
                                              float* __restrict__ Y, int N) {
  constexpr int NC = OUT / 4;      // col-threads (32 or 16)
  constexpr int MR = 256 / NC;     // row-threads (8 or 16)
  constexpr int MT = MR * 4;       // row tile (32 or 64)
  constexpr int KT = 32;
  constexpr int XP = MT + 4;       // pad keeps 16B alignment of Xt rows
  __shared__ float Ws[KT][OUT];
  __shared__ float Xt[KT][XP];
  int t = threadIdx.x;
  int row0 = blockIdx.x * MT;
  int tc = t % NC, tr = t / NC;
  float acc[4][4] = {};
  for (int kb = 0; kb < IN; kb += KT) {
    for (int i = t * 4; i < KT * OUT; i += 1024) {
      int k = i / OUT, c = i % OUT;
      *(float4*)&Ws[k][c] = *(const float4*)&W[(size_t)(kb + k) * OUT + c];
    }
    for (int i = t * 4; i < MT * KT; i += 1024) {
      int r = i / KT, k = i % KT;
      int gr = row0 + r;
      float4 v = make_float4(0.f, 0.f, 0.f, 0.f);
      if (gr < N) v = *(const float4*)&X[(size_t)gr * IN + kb + k];
      Xt[k + 0][r] = v.x; Xt[k + 1][r] = v.y; Xt[k + 2][r] = v.z; Xt[k + 3][r] = v.w;
    }
    __syncthreads();
#pragma unroll
    for (int k = 0; k < KT; ++k) {
      float4 xv = *(const float4*)&Xt[k][4 * tr];
      float4 wv = *(const float4*)&Ws[k][4 * tc];
      float xa[4] = {xv.x, xv.y, xv.z, xv.w};
      float wa[4] = {wv.x, wv.y, wv.z, wv.w};
#pragma unroll
      for (int j = 0; j < 4; ++j)
#pragma unroll
        for (int i2 = 0; i2 < 4; ++i2)
          acc[j][i2] += xa[j] * wa[i2];
    }
    __syncthreads();
  }
#pragma unroll
  for (int j = 0; j < 4; ++j) {
    int r = row0 + 4 * tr + j;
    if (r < N)
      *(float4*)&Y[(size_t)r * OUT + 4 * tc] =
          make_float4(acc[j][0], acc[j][1], acc[j][2], acc[j][3]);
  }
}

// ---------------- normalized aggregation (gather-only SpMM row) ----------------
// Out[n,c] = act( dinv[n] * ( H[n,c]*dinv[n] + sum_e H[col,c]*dinv[col] ) + bias[c] )
// 8-deep edge pipeline: 8 independent gathers in flight per thread.

template <int C, bool RELU>
__global__ __launch_bounds__(256) void k_agg(const float* __restrict__ H,
                                             const int* __restrict__ rowptr,
                                             const int* __restrict__ col,
                                             const float* __restrict__ wsrc,
                                             const float* __restrict__ dinv,
                                             const float* __restrict__ bias,
                                             float* __restrict__ Out, int N) {
  constexpr int NPB = 256 / C;  // nodes per block
  int n = blockIdx.x * NPB + threadIdx.x / C;
  if (n >= N) return;
  int c = threadIdx.x % C;
  float dn = dinv[n];
  int p = rowptr[n], pend = rowptr[n + 1];
  float acc = H[(size_t)n * C + c] * dn;  // self loop (x dn again below)
  for (; p + 8 <= pend; p += 8) {
    int s[8]; float w[8], hv[8];
#pragma unroll
    for (int j = 0; j < 8; ++j) { s[j] = col[p + j]; w[j] = wsrc[p + j]; }
#pragma unroll
    for (int j = 0; j < 8; ++j) hv[j] = H[(size_t)s[j] * C + c];
#pragma unroll
    for (int j = 0; j < 8; ++j) acc += hv[j] * w[j];
  }
  for (; p < pend; ++p) acc += H[(size_t)col[p] * C + c] * wsrc[p];
  float v = dn * acc + bias[c];
  if (RELU) v = fmaxf(v, 0.f);
  Out[(size_t)n * C + c] = v;
}

// ---------------- decode: logits[i] = dot(z[a[i]], z[b[i]]) ----------------

__global__ __launch_bounds__(256) void k_decode(const float4* __restrict__ Z4,
                                                const int* __restrict__ ia,
                                                const int* __restrict__ ib,
                                                float* __restrict__ out, int L) {
  int t = blockIdx.x * 256 + threadIdx.x;
  int i = t >> 4;  // pair index, 16 threads each
  if (i >= L) return;
  int e = t & 15;
  int a = ia[i], b = ib[i];
  float4 za = Z4[(size_t)a * (OUT_CH / 4) + e];
  float4 zb = Z4[(size_t)b * (OUT_CH / 4) + e];
  float p = za.x * zb.x + za.y * zb.y + za.z * zb.z + za.w * zb.w;
  p += __shfl_xor(p, 1);
  p += __shfl_xor(p, 2);
  p += __shfl_xor(p, 4);
  p += __shfl_xor(p, 8);
  if (e == 0) out[i] = p;
}

extern "C" void kernel_launch(void* const* d_in, const int* in_sizes, int n_in,
                              void* d_out, int out_size, void* d_ws, size_t ws_size,
                              hipStream_t stream) {
  const float* x   = (const float*)d_in[0];
  const int*   ei  = (const int*)d_in[1];
  const int*   eli = (const int*)d_in[2];
  const float* W1  = (const float*)d_in[3];
  const float* b1  = (const float*)d_in[4];
  const float* W2  = (const float*)d_in[5];
  const float* b2  = (const float*)d_in[6];
  float* logits = (float*)d_out;

  int N = in_sizes[0] / IN_CH;
  int E = in_sizes[1] / 2;
  int L = in_sizes[2] / 2;
  const int* src = ei;
  const int* dst = ei + E;
  const int* la  = eli;
  const int* lb  = eli + L;

  char* ws = (char*)d_ws;
  size_t off = 0;
  auto alloc = [&](size_t bytes) {
    void* p = ws + off;
    off = (off + bytes + 255) & ~(size_t)255;
    return p;
  };
  int*   cnt    = (int*)alloc((size_t)N * 4);
  int*   cursor = (int*)alloc((size_t)N * 4);
  int*   rowptr = (int*)alloc((size_t)(N + 1) * 4);
  float* dinv   = (float*)alloc((size_t)N * 4);
  int*   col    = (int*)alloc((size_t)E * 4);
  float* wsrc   = (float*)alloc((size_t)E * 4);
  float* h      = (float*)alloc((size_t)N * HID_CH * 4);
  float* hr     = (float*)alloc((size_t)N * HID_CH * 4);
  float* h2     = (float*)alloc((size_t)N * OUT_CH * 4);
  float* z      = (float*)alloc((size_t)N * OUT_CH * 4);
  int*   bsum   = (int*)alloc(256 * 4);
  int*   boff   = (int*)alloc(256 * 4);

  // atomics + cursors must start at zero EVERY call (harness doesn't re-poison)
  hipMemsetAsync(cnt, 0, (size_t)N * 4, stream);
  hipMemsetAsync(cursor, 0, (size_t)N * 4, stream);

  const int TB = 256;
  int nscan = (N + SCAN_CHUNK - 1) / SCAN_CHUNK;
  k_count<<<(E / 4 + TB - 1) / TB, TB, 0, stream>>>(dst, cnt, E);
  k_dinv <<<(N + TB - 1) / TB, TB, 0, stream>>>(cnt, dinv, N);
  k_scan_part<<<nscan, 256, 0, stream>>>(cnt, bsum, N);
  k_scan_top <<<1, 256, 0, stream>>>(bsum, boff, nscan);
  k_scan_fill<<<nscan, 256, 0, stream>>>(cnt, boff, rowptr, N, E);
  k_fill <<<(E / 4 + TB - 1) / TB, TB, 0, stream>>>(src, dst, rowptr, cursor, dinv, col, wsrc, E);

  // layer 1: h = x@W1 ; hr = relu(norm-agg(h) + b1)
  k_gemm<IN_CH, HID_CH><<<(N + 31) / 32, 256, 0, stream>>>(x, W1, h, N);
  k_agg<HID_CH, true><<<(N + 1) / 2, 256, 0, stream>>>(h, rowptr, col, wsrc, dinv, b1, hr, N);

  // layer 2: h2 = hr@W2 ; z = norm-agg(h2) + b2
  k_gemm<HID_CH, OUT_CH><<<(N + 63) / 64, 256, 0, stream>>>(hr, W2, h2, N);
  k_agg<OUT_CH, false><<<(N + 3) / 4, 256, 0, stream>>>(h2, rowptr, col, wsrc, dinv, b2, z, N);

  // decode
  k_decode<<<((size_t)L * 16 + 255) / 256, 256, 0, stream>>>((const float4*)z, la, lb, logits, L);
}

// Round 4
// 178.531 us; speedup vs baseline: 2.1179x; 1.2412x over previous
//
#include <hip/hip_runtime.h>
#include <hip/hip_bf16.h>

constexpr int IN_CH  = 128;
constexpr int HID_CH = 128;
constexpr int OUT_CH = 64;
constexpr int SCAN_CHUNK = 1024;   // elements per scan block (256 thr x 4)

// ---------------- bf16 pack/unpack helpers ----------------

__device__ inline unsigned pack_bf16x2(float lo, float hi) {
  __hip_bfloat16 a = __float2bfloat16(lo);   // RN
  __hip_bfloat16 b = __float2bfloat16(hi);
  unsigned short ua = *reinterpret_cast<unsigned short*>(&a);
  unsigned short ub = *reinterpret_cast<unsigned short*>(&b);
  return (unsigned)ua | ((unsigned)ub << 16);
}
__device__ inline float bf_lo(unsigned u) { return __uint_as_float(u << 16); }
__device__ inline float bf_hi(unsigned u) { return __uint_as_float(u & 0xffff0000u); }

// ---------------- CSR build ----------------

__global__ void k_count(const int* __restrict__ dst, int* __restrict__ cnt, int E) {
  int e = (blockIdx.x * blockDim.x + threadIdx.x) * 4;
  if (e + 3 < E) {
    int4 v = *(const int4*)&dst[e];
    atomicAdd(&cnt[v.x], 1); atomicAdd(&cnt[v.y], 1);
    atomicAdd(&cnt[v.z], 1); atomicAdd(&cnt[v.w], 1);
  } else {
    for (int j = 0; j < 4 && e + j < E; ++j) atomicAdd(&cnt[dst[e + j]], 1);
  }
}

__global__ void k_dinv(const int* __restrict__ cnt, float* __restrict__ dinv, int N) {
  int n = blockIdx.x * blockDim.x + threadIdx.x;
  if (n < N) dinv[n] = rsqrtf((float)cnt[n] + 1.0f);  // +1 self loop
}

// 3-phase multi-block exclusive scan of cnt -> rowptr
__global__ __launch_bounds__(256) void k_scan_part(const int* __restrict__ cnt,
                                                   int* __restrict__ bsum, int N) {
  int t = threadIdx.x;
  int base = blockIdx.x * SCAN_CHUNK + t * 4;
  int s = 0;
  if (base + 3 < N) {
    int4 v = *(const int4*)&cnt[base];
    s = v.x + v.y + v.z + v.w;
  } else {
    for (int j = 0; j < 4; ++j) if (base + j < N) s += cnt[base + j];
  }
  __shared__ int red[256];
  red[t] = s; __syncthreads();
  for (int off = 128; off; off >>= 1) {
    if (t < off) red[t] += red[t + off];
    __syncthreads();
  }
  if (t == 0) bsum[blockIdx.x] = red[0];
}

__global__ __launch_bounds__(256) void k_scan_top(const int* __restrict__ bsum,
                                                  int* __restrict__ boff, int nblk) {
  int t = threadIdx.x;
  __shared__ int s[256];
  int v = (t < nblk) ? bsum[t] : 0;
  s[t] = v; __syncthreads();
  for (int off = 1; off < 256; off <<= 1) {
    int add = (t >= off) ? s[t - off] : 0;
    __syncthreads();
    s[t] += add;
    __syncthreads();
  }
  if (t < nblk) boff[t] = s[t] - v;  // exclusive
}

__global__ __launch_bounds__(256) void k_scan_fill(const int* __restrict__ cnt,
                                                   const int* __restrict__ boff,
                                                   int* __restrict__ rowptr, int N, int E) {
  int t = threadIdx.x;
  int base = blockIdx.x * SCAN_CHUNK + t * 4;
  int v[4] = {0, 0, 0, 0};
  if (base + 3 < N) {
    int4 q = *(const int4*)&cnt[base];
    v[0] = q.x; v[1] = q.y; v[2] = q.z; v[3] = q.w;
  } else {
    for (int j = 0; j < 4; ++j) if (base + j < N) v[j] = cnt[base + j];
  }
  int mysum = v[0] + v[1] + v[2] + v[3];
  __shared__ int s[256];
  s[t] = mysum; __syncthreads();
  for (int off = 1; off < 256; off <<= 1) {
    int add = (t >= off) ? s[t - off] : 0;
    __syncthreads();
    s[t] += add;
    __syncthreads();
  }
  int run = boff[blockIdx.x] + s[t] - mysum;  // exclusive prefix for my 4
  for (int j = 0; j < 4; ++j) {
    if (base + j < N) rowptr[base + j] = run;
    run += v[j];
  }
  if (blockIdx.x == 0 && t == 0) rowptr[N] = E;
}

__global__ void k_fill(const int* __restrict__ src, const int* __restrict__ dst,
                       const int* __restrict__ rowptr, int* __restrict__ cursor,
                       int* __restrict__ col, int E) {
  int e0 = (blockIdx.x * blockDim.x + threadIdx.x) * 4;
  if (e0 >= E) return;
  int sv[4], dv[4];
  if (e0 + 3 < E) {
    *(int4*)sv = *(const int4*)&src[e0];
    *(int4*)dv = *(const int4*)&dst[e0];
    for (int j = 0; j < 4; ++j) {
      int p = rowptr[dv[j]] + atomicAdd(&cursor[dv[j]], 1);
      col[p] = sv[j];
    }
  } else {
    for (int j = 0; j < 4 && e0 + j < E; ++j) {
      int d = dst[e0 + j];
      int p = rowptr[d] + atomicAdd(&cursor[d], 1);
      col[p] = src[e0 + j];
    }
  }
}

// ---------------- dense GEMM, register-tiled 4x4 (vector fp32) ----------------
// Y_bf16[r][c] = bf16( (X[r,:] @ W[:,c]) * scale[r] )   -- dinv pre-scaling fused

template <int IN, int OUT>
__global__ __launch_bounds__(256) void k_gemm(const float* __restrict__ X,
                                              const float* __restrict__ W,
                                              const float* __restrict__ scale,
                                              unsigned short* __restrict__ Y, int N) {
  constexpr int NC = OUT / 4;      // col-threads (32 or 16)
  constexpr int MR = 256 / NC;     // row-threads (8 or 16)
  constexpr int MT = MR * 4;       // row tile (32 or 64)
  constexpr int KT = 32;
  constexpr int XP = MT + 4;       // pad keeps 16B alignment of Xt rows
  __shared__ float Ws[KT][OUT];
  __shared__ float Xt[KT][XP];
  int t = threadIdx.x;
  int row0 = blockIdx.x * MT;
  int tc = t % NC, tr = t / NC;
  float acc[4][4] = {};
  for (int kb = 0; kb < IN; kb += KT) {
    for (int i = t * 4; i < KT * OUT; i += 1024) {
      int k = i / OUT, c = i % OUT;
      *(float4*)&Ws[k][c] = *(const float4*)&W[(size_t)(kb + k) * OUT + c];
    }
    for (int i = t * 4; i < MT * KT; i += 1024) {
      int r = i / KT, k = i % KT;
      int gr = row0 + r;
      float4 v = make_float4(0.f, 0.f, 0.f, 0.f);
      if (gr < N) v = *(const float4*)&X[(size_t)gr * IN + kb + k];
      Xt[k + 0][r] = v.x; Xt[k + 1][r] = v.y; Xt[k + 2][r] = v.z; Xt[k + 3][r] = v.w;
    }
    __syncthreads();
#pragma unroll
    for (int k = 0; k < KT; ++k) {
      float4 xv = *(const float4*)&Xt[k][4 * tr];
      float4 wv = *(const float4*)&Ws[k][4 * tc];
      float xa[4] = {xv.x, xv.y, xv.z, xv.w};
      float wa[4] = {wv.x, wv.y, wv.z, wv.w};
#pragma unroll
      for (int j = 0; j < 4; ++j)
#pragma unroll
        for (int i2 = 0; i2 < 4; ++i2)
          acc[j][i2] += xa[j] * wa[i2];
    }
    __syncthreads();
  }
#pragma unroll
  for (int j = 0; j < 4; ++j) {
    int r = row0 + 4 * tr + j;
    if (r < N) {
      float s = scale[r];
      uint2 w;
      w.x = pack_bf16x2(acc[j][0] * s, acc[j][1] * s);
      w.y = pack_bf16x2(acc[j][2] * s, acc[j][3] * s);
      *(uint2*)&Y[(size_t)r * OUT + 4 * tc] = w;
    }
  }
}

// ---------------- aggregation, 128ch bf16 table, fp32 out ----------------
// HS[n] holds bf16(h[n]*dinv[n]); Out[n,c] = relu(dn*(HS[n,c] + sum HS[col,c]) + b[c])
// One wave per node; lane l owns channels 2l, 2l+1; one 256B gather per edge.

__global__ __launch_bounds__(256) void k_agg128(const unsigned* __restrict__ HS,
                                                const int* __restrict__ rowptr,
                                                const int* __restrict__ col,
                                                const float* __restrict__ dinv,
                                                const float* __restrict__ bias,
                                                float* __restrict__ Out, int N) {
  int n = blockIdx.x * 4 + (threadIdx.x >> 6);
  if (n >= N) return;
  int l = threadIdx.x & 63;
  float dn = dinv[n];
  unsigned u0 = HS[(size_t)n * 64 + l];
  float ax = bf_lo(u0), ay = bf_hi(u0);
  int p = rowptr[n], pend = rowptr[n + 1];
  for (; p + 8 <= pend; p += 8) {
    int s[8]; unsigned g[8];
#pragma unroll
    for (int j = 0; j < 8; ++j) s[j] = col[p + j];
#pragma unroll
    for (int j = 0; j < 8; ++j) g[j] = HS[(size_t)s[j] * 64 + l];
#pragma unroll
    for (int j = 0; j < 8; ++j) { ax += bf_lo(g[j]); ay += bf_hi(g[j]); }
  }
  for (; p < pend; ++p) {
    unsigned g = HS[(size_t)col[p] * 64 + l];
    ax += bf_lo(g); ay += bf_hi(g);
  }
  float2 b2 = ((const float2*)bias)[l];
  float vx = fmaxf(dn * ax + b2.x, 0.f);
  float vy = fmaxf(dn * ay + b2.y, 0.f);
  ((float2*)Out)[(size_t)n * 64 + l] = make_float2(vx, vy);
}

// ---------------- aggregation, 64ch bf16 table, bf16 out (no relu) ----------------
// 32-thread group per node; lane g owns channels 2g, 2g+1; one 128B gather per edge.

__global__ __launch_bounds__(256) void k_agg64(const unsigned* __restrict__ HS,
                                               const int* __restrict__ rowptr,
                                               const int* __restrict__ col,
                                               const float* __restrict__ dinv,
                                               const float* __restrict__ bias,
                                               unsigned* __restrict__ Zu, int N) {
  int n = blockIdx.x * 8 + (threadIdx.x >> 5);
  if (n >= N) return;
  int g = threadIdx.x & 31;
  float dn = dinv[n];
  unsigned u0 = HS[(size_t)n * 32 + g];
  float ax = bf_lo(u0), ay = bf_hi(u0);
  int p = rowptr[n], pend = rowptr[n + 1];
  for (; p + 8 <= pend; p += 8) {
    int s[8]; unsigned q[8];
#pragma unroll
    for (int j = 0; j < 8; ++j) s[j] = col[p + j];
#pragma unroll
    for (int j = 0; j < 8; ++j) q[j] = HS[(size_t)s[j] * 32 + g];
#pragma unroll
    for (int j = 0; j < 8; ++j) { ax += bf_lo(q[j]); ay += bf_hi(q[j]); }
  }
  for (; p < pend; ++p) {
    unsigned q = HS[(size_t)col[p] * 32 + g];
    ax += bf_lo(q); ay += bf_hi(q);
  }
  float2 b2 = ((const float2*)bias)[g];
  Zu[(size_t)n * 32 + g] = pack_bf16x2(dn * ax + b2.x, dn * ay + b2.y);
}

// ---------------- decode: logits[i] = dot(z[a[i]], z[b[i]]), z bf16 ----------------
// 8 lanes per pair; each lane loads uint4 (8 channels) per side.

__global__ __launch_bounds__(256) void k_decode(const uint4* __restrict__ Z,
                                                const int* __restrict__ ia,
                                                const int* __restrict__ ib,
                                                float* __restrict__ out, int L) {
  int t = blockIdx.x * 256 + threadIdx.x;
  int i = t >> 3;
  if (i >= L) return;
  int e = t & 7;
  int a = ia[i], b = ib[i];
  uint4 za = Z[(size_t)a * 8 + e];
  uint4 zb = Z[(size_t)b * 8 + e];
  float p = bf_lo(za.x) * bf_lo(zb.x) + bf_hi(za.x) * bf_hi(zb.x)
          + bf_lo(za.y) * bf_lo(zb.y) + bf_hi(za.y) * bf_hi(zb.y)
          + bf_lo(za.z) * bf_lo(zb.z) + bf_hi(za.z) * bf_hi(zb.z)
          + bf_lo(za.w) * bf_lo(zb.w) + bf_hi(za.w) * bf_hi(zb.w);
  p += __shfl_xor(p, 1);
  p += __shfl_xor(p, 2);
  p += __shfl_xor(p, 4);
  if (e == 0) out[i] = p;
}

extern "C" void kernel_launch(void* const* d_in, const int* in_sizes, int n_in,
                              void* d_out, int out_size, void* d_ws, size_t ws_size,
                              hipStream_t stream) {
  const float* x   = (const float*)d_in[0];
  const int*   ei  = (const int*)d_in[1];
  const int*   eli = (const int*)d_in[2];
  const float* W1  = (const float*)d_in[3];
  const float* b1  = (const float*)d_in[4];
  const float* W2  = (const float*)d_in[5];
  const float* b2  = (const float*)d_in[6];
  float* logits = (float*)d_out;

  int N = in_sizes[0] / IN_CH;
  int E = in_sizes[1] / 2;
  int L = in_sizes[2] / 2;
  const int* src = ei;
  const int* dst = ei + E;
  const int* la  = eli;
  const int* lb  = eli + L;

  char* ws = (char*)d_ws;
  size_t off = 0;
  auto alloc = [&](size_t bytes) {
    void* p = ws + off;
    off = (off + bytes + 255) & ~(size_t)255;
    return p;
  };
  int*      cnt    = (int*)alloc((size_t)N * 4);
  int*      cursor = (int*)alloc((size_t)N * 4);
  int*      rowptr = (int*)alloc((size_t)(N + 1) * 4);
  float*    dinv   = (float*)alloc((size_t)N * 4);
  int*      col    = (int*)alloc((size_t)E * 4);
  unsigned short* hs  = (unsigned short*)alloc((size_t)N * HID_CH * 2);  // bf16 h*dinv
  float*    hr     = (float*)alloc((size_t)N * HID_CH * 4);              // fp32 relu out
  unsigned short* h2s = (unsigned short*)alloc((size_t)N * OUT_CH * 2);  // bf16 h2*dinv
  unsigned* zu     = (unsigned*)alloc((size_t)N * OUT_CH * 2);           // bf16 z
  int*      bsum   = (int*)alloc(256 * 4);
  int*      boff   = (int*)alloc(256 * 4);

  // atomics + cursors must start at zero EVERY call (harness doesn't re-poison)
  hipMemsetAsync(cnt, 0, (size_t)N * 4, stream);
  hipMemsetAsync(cursor, 0, (size_t)N * 4, stream);

  const int TB = 256;
  int nscan = (N + SCAN_CHUNK - 1) / SCAN_CHUNK;
  k_count<<<(E / 4 + TB - 1) / TB, TB, 0, stream>>>(dst, cnt, E);
  k_dinv <<<(N + TB - 1) / TB, TB, 0, stream>>>(cnt, dinv, N);
  k_scan_part<<<nscan, 256, 0, stream>>>(cnt, bsum, N);
  k_scan_top <<<1, 256, 0, stream>>>(bsum, boff, nscan);
  k_scan_fill<<<nscan, 256, 0, stream>>>(cnt, boff, rowptr, N, E);
  k_fill <<<(E / 4 + TB - 1) / TB, TB, 0, stream>>>(src, dst, rowptr, cursor, col, E);

  // layer 1: hs = bf16((x@W1)*dinv) ; hr = relu(dn*(hs[n]+sum hs[col]) + b1)
  k_gemm<IN_CH, HID_CH><<<(N + 31) / 32, 256, 0, stream>>>(x, W1, dinv, hs, N);
  k_agg128<<<(N + 3) / 4, 256, 0, stream>>>((const unsigned*)hs, rowptr, col, dinv, b1, hr, N);

  // layer 2: h2s = bf16((hr@W2)*dinv) ; z = bf16(dn*(h2s[n]+sum h2s[col]) + b2)
  k_gemm<HID_CH, OUT_CH><<<(N + 63) / 64, 256, 0, stream>>>(hr, W2, dinv, h2s, N);
  k_agg64<<<(N + 7) / 8, 256, 0, stream>>>((const unsigned*)h2s, rowptr, col, dinv, b2, zu, N);

  // decode
  k_decode<<<((size_t)L * 8 + 255) / 256, 256, 0, stream>>>((const uint4*)zu, la, lb, logits, L);
}

// Round 5
// 173.199 us; speedup vs baseline: 2.1831x; 1.0308x over previous
//
#include <hip/hip_runtime.h>
#include <hip/hip_bf16.h>

constexpr int IN_CH  = 128;
constexpr int HID_CH = 128;
constexpr int OUT_CH = 64;
constexpr int SCAN_CHUNK = 1024;   // elements per scan block (256 thr x 4)

// ---------------- bf16 pack/unpack helpers ----------------

__device__ inline unsigned pack_bf16x2(float lo, float hi) {
  __hip_bfloat16 a = __float2bfloat16(lo);   // RN
  __hip_bfloat16 b = __float2bfloat16(hi);
  unsigned short ua = *reinterpret_cast<unsigned short*>(&a);
  unsigned short ub = *reinterpret_cast<unsigned short*>(&b);
  return (unsigned)ua | ((unsigned)ub << 16);
}
__device__ inline float bf_lo(unsigned u) { return __uint_as_float(u << 16); }
__device__ inline float bf_hi(unsigned u) { return __uint_as_float(u & 0xffff0000u); }

// ---------------- workspace zeroing (replaces pathological rocclr fill) ----------------

__global__ __launch_bounds__(256) void k_zero(int* __restrict__ a, int* __restrict__ b, int n) {
  int i = (blockIdx.x * 256 + threadIdx.x) * 4;
  if (i + 3 < n) {
    *(int4*)&a[i] = make_int4(0, 0, 0, 0);
    *(int4*)&b[i] = make_int4(0, 0, 0, 0);
  } else {
    for (int j = 0; j < 4 && i + j < n; ++j) { a[i + j] = 0; b[i + j] = 0; }
  }
}

// ---------------- CSR build ----------------

__global__ void k_count(const int* __restrict__ dst, int* __restrict__ cnt, int E) {
  int e = (blockIdx.x * blockDim.x + threadIdx.x) * 4;
  if (e + 3 < E) {
    int4 v = *(const int4*)&dst[e];
    atomicAdd(&cnt[v.x], 1); atomicAdd(&cnt[v.y], 1);
    atomicAdd(&cnt[v.z], 1); atomicAdd(&cnt[v.w], 1);
  } else {
    for (int j = 0; j < 4 && e + j < E; ++j) atomicAdd(&cnt[dst[e + j]], 1);
  }
}

// phase 1 of scan, fused with dinv computation (both only read cnt)
__global__ __launch_bounds__(256) void k_scan_part(const int* __restrict__ cnt,
                                                   int* __restrict__ bsum,
                                                   float* __restrict__ dinv, int N) {
  int t = threadIdx.x;
  int base = blockIdx.x * SCAN_CHUNK + t * 4;
  int s = 0;
  if (base + 3 < N) {
    int4 v = *(const int4*)&cnt[base];
    s = v.x + v.y + v.z + v.w;
    float4 d;
    d.x = rsqrtf((float)v.x + 1.0f);
    d.y = rsqrtf((float)v.y + 1.0f);
    d.z = rsqrtf((float)v.z + 1.0f);
    d.w = rsqrtf((float)v.w + 1.0f);
    *(float4*)&dinv[base] = d;
  } else {
    for (int j = 0; j < 4; ++j)
      if (base + j < N) {
        int c = cnt[base + j];
        s += c;
        dinv[base + j] = rsqrtf((float)c + 1.0f);
      }
  }
  __shared__ int red[256];
  red[t] = s; __syncthreads();
  for (int off = 128; off; off >>= 1) {
    if (t < off) red[t] += red[t + off];
    __syncthreads();
  }
  if (t == 0) bsum[blockIdx.x] = red[0];
}

__global__ __launch_bounds__(256) void k_scan_top(const int* __restrict__ bsum,
                                                  int* __restrict__ boff, int nblk) {
  int t = threadIdx.x;
  __shared__ int s[256];
  int v = (t < nblk) ? bsum[t] : 0;
  s[t] = v; __syncthreads();
  for (int off = 1; off < 256; off <<= 1) {
    int add = (t >= off) ? s[t - off] : 0;
    __syncthreads();
    s[t] += add;
    __syncthreads();
  }
  if (t < nblk) boff[t] = s[t] - v;  // exclusive
}

__global__ __launch_bounds__(256) void k_scan_fill(const int* __restrict__ cnt,
                                                   const int* __restrict__ boff,
                                                   int* __restrict__ rowptr, int N, int E) {
  int t = threadIdx.x;
  int base = blockIdx.x * SCAN_CHUNK + t * 4;
  int v[4] = {0, 0, 0, 0};
  if (base + 3 < N) {
    int4 q = *(const int4*)&cnt[base];
    v[0] = q.x; v[1] = q.y; v[2] = q.z; v[3] = q.w;
  } else {
    for (int j = 0; j < 4; ++j) if (base + j < N) v[j] = cnt[base + j];
  }
  int mysum = v[0] + v[1] + v[2] + v[3];
  __shared__ int s[256];
  s[t] = mysum; __syncthreads();
  for (int off = 1; off < 256; off <<= 1) {
    int add = (t >= off) ? s[t - off] : 0;
    __syncthreads();
    s[t] += add;
    __syncthreads();
  }
  int run = boff[blockIdx.x] + s[t] - mysum;  // exclusive prefix for my 4
  for (int j = 0; j < 4; ++j) {
    if (base + j < N) rowptr[base + j] = run;
    run += v[j];
  }
  if (blockIdx.x == 0 && t == 0) rowptr[N] = E;
}

__global__ void k_fill(const int* __restrict__ src, const int* __restrict__ dst,
                       const int* __restrict__ rowptr, int* __restrict__ cursor,
                       int* __restrict__ col, int E) {
  int e0 = (blockIdx.x * blockDim.x + threadIdx.x) * 4;
  if (e0 >= E) return;
  int sv[4], dv[4];
  if (e0 + 3 < E) {
    *(int4*)sv = *(const int4*)&src[e0];
    *(int4*)dv = *(const int4*)&dst[e0];
    for (int j = 0; j < 4; ++j) {
      int p = rowptr[dv[j]] + atomicAdd(&cursor[dv[j]], 1);
      col[p] = sv[j];
    }
  } else {
    for (int j = 0; j < 4 && e0 + j < E; ++j) {
      int d = dst[e0 + j];
      int p = rowptr[d] + atomicAdd(&cursor[d], 1);
      col[p] = src[e0 + j];
    }
  }
}

// ---------------- dense GEMM, register-tiled 4x4 (vector fp32) ----------------
// Y_bf16[r][c] = bf16( (X[r,:] @ W[:,c]) * scale[r] )   -- dinv pre-scaling fused

template <int IN, int OUT>
__global__ __launch_bounds__(256) void k_gemm(const float* __restrict__ X,
                                              const float* __restrict__ W,
                                              const float* __restrict__ scale,
                                              unsigned short* __restrict__ Y, int N) {
  constexpr int NC = OUT / 4;      // col-threads (32 or 16)
  constexpr int MR = 256 / NC;     // row-threads (8 or 16)
  constexpr int MT = MR * 4;       // row tile (32 or 64)
  constexpr int KT = 32;
  constexpr int XP = MT + 4;       // pad keeps 16B alignment of Xt rows
  __shared__ float Ws[KT][OUT];
  __shared__ float Xt[KT][XP];
  int t = threadIdx.x;
  int row0 = blockIdx.x * MT;
  int tc = t % NC, tr = t / NC;
  float acc[4][4] = {};
  for (int kb = 0; kb < IN; kb += KT) {
    for (int i = t * 4; i < KT * OUT; i += 1024) {
      int k = i / OUT, c = i % OUT;
      *(float4*)&Ws[k][c] = *(const float4*)&W[(size_t)(kb + k) * OUT + c];
    }
    for (int i = t * 4; i < MT * KT; i += 1024) {
      int r = i / KT, k = i % KT;
      int gr = row0 + r;
      float4 v = make_float4(0.f, 0.f, 0.f, 0.f);
      if (gr < N) v = *(const float4*)&X[(size_t)gr * IN + kb + k];
      Xt[k + 0][r] = v.x; Xt[k + 1][r] = v.y; Xt[k + 2][r] = v.z; Xt[k + 3][r] = v.w;
    }
    __syncthreads();
#pragma unroll
    for (int k = 0; k < KT; ++k) {
      float4 xv = *(const float4*)&Xt[k][4 * tr];
      float4 wv = *(const float4*)&Ws[k][4 * tc];
      float xa[4] = {xv.x, xv.y, xv.z, xv.w};
      float wa[4] = {wv.x, wv.y, wv.z, wv.w};
#pragma unroll
      for (int j = 0; j < 4; ++j)
#pragma unroll
        for (int i2 = 0; i2 < 4; ++i2)
          acc[j][i2] += xa[j] * wa[i2];
    }
    __syncthreads();
  }
#pragma unroll
  for (int j = 0; j < 4; ++j) {
    int r = row0 + 4 * tr + j;
    if (r < N) {
      float s = scale[r];
      uint2 w;
      w.x = pack_bf16x2(acc[j][0] * s, acc[j][1] * s);
      w.y = pack_bf16x2(acc[j][2] * s, acc[j][3] * s);
      *(uint2*)&Y[(size_t)r * OUT + 4 * tc] = w;
    }
  }
}

// ---------------- aggregation, 128ch bf16 table, fp32 out ----------------
// HS[n] holds bf16(h[n]*dinv[n]); Out[n,c] = relu(dn*(HS[n,c] + sum HS[col,c]) + b[c])
// One wave per node; lane l owns channels 2l, 2l+1; one 256B gather per edge.

__global__ __launch_bounds__(256) void k_agg128(const unsigned* __restrict__ HS,
                                                const int* __restrict__ rowptr,
                                                const int* __restrict__ col,
                                                const float* __restrict__ dinv,
                                                const float* __restrict__ bias,
                                                float* __restrict__ Out, int N) {
  int n = blockIdx.x * 4 + (threadIdx.x >> 6);
  if (n >= N) return;
  int l = threadIdx.x & 63;
  float dn = dinv[n];
  unsigned u0 = HS[(size_t)n * 64 + l];
  float ax = bf_lo(u0), ay = bf_hi(u0);
  int p = rowptr[n], pend = rowptr[n + 1];
  for (; p + 8 <= pend; p += 8) {
    int s[8]; unsigned g[8];
#pragma unroll
    for (int j = 0; j < 8; ++j) s[j] = col[p + j];
#pragma unroll
    for (int j = 0; j < 8; ++j) g[j] = HS[(size_t)s[j] * 64 + l];
#pragma unroll
    for (int j = 0; j < 8; ++j) { ax += bf_lo(g[j]); ay += bf_hi(g[j]); }
  }
  for (; p < pend; ++p) {
    unsigned g = HS[(size_t)col[p] * 64 + l];
    ax += bf_lo(g); ay += bf_hi(g);
  }
  float2 b2 = ((const float2*)bias)[l];
  float vx = fmaxf(dn * ax + b2.x, 0.f);
  float vy = fmaxf(dn * ay + b2.y, 0.f);
  ((float2*)Out)[(size_t)n * 64 + l] = make_float2(vx, vy);
}

// ---------------- aggregation, 64ch bf16 table, bf16 out (no relu) ----------------
// 32-thread group per node; lane g owns channels 2g, 2g+1; one 128B gather per edge.

__global__ __launch_bounds__(256) void k_agg64(const unsigned* __restrict__ HS,
                                               const int* __restrict__ rowptr,
                                               const int* __restrict__ col,
                                               const float* __restrict__ dinv,
                                               const float* __restrict__ bias,
                                               unsigned* __restrict__ Zu, int N) {
  int n = blockIdx.x * 8 + (threadIdx.x >> 5);
  if (n >= N) return;
  int g = threadIdx.x & 31;
  float dn = dinv[n];
  unsigned u0 = HS[(size_t)n * 32 + g];
  float ax = bf_lo(u0), ay = bf_hi(u0);
  int p = rowptr[n], pend = rowptr[n + 1];
  for (; p + 8 <= pend; p += 8) {
    int s[8]; unsigned q[8];
#pragma unroll
    for (int j = 0; j < 8; ++j) s[j] = col[p + j];
#pragma unroll
    for (int j = 0; j < 8; ++j) q[j] = HS[(size_t)s[j] * 32 + g];
#pragma unroll
    for (int j = 0; j < 8; ++j) { ax += bf_lo(q[j]); ay += bf_hi(q[j]); }
  }
  for (; p < pend; ++p) {
    unsigned q = HS[(size_t)col[p] * 32 + g];
    ax += bf_lo(q); ay += bf_hi(q);
  }
  float2 b2 = ((const float2*)bias)[g];
  Zu[(size_t)n * 32 + g] = pack_bf16x2(dn * ax + b2.x, dn * ay + b2.y);
}

// ---------------- decode: logits[i] = dot(z[a[i]], z[b[i]]), z bf16 ----------------
// 8 lanes per pair; each lane loads uint4 (8 channels) per side.

__global__ __launch_bounds__(256) void k_decode(const uint4* __restrict__ Z,
                                                const int* __restrict__ ia,
                                                const int* __restrict__ ib,
                                                float* __restrict__ out, int L) {
  int t = blockIdx.x * 256 + threadIdx.x;
  int i = t >> 3;
  if (i >= L) return;
  int e = t & 7;
  int a = ia[i], b = ib[i];
  uint4 za = Z[(size_t)a * 8 + e];
  uint4 zb = Z[(size_t)b * 8 + e];
  float p = bf_lo(za.x) * bf_lo(zb.x) + bf_hi(za.x) * bf_hi(zb.x)
          + bf_lo(za.y) * bf_lo(zb.y) + bf_hi(za.y) * bf_hi(zb.y)
          + bf_lo(za.z) * bf_lo(zb.z) + bf_hi(za.z) * bf_hi(zb.z)
          + bf_lo(za.w) * bf_lo(zb.w) + bf_hi(za.w) * bf_hi(zb.w);
  p += __shfl_xor(p, 1);
  p += __shfl_xor(p, 2);
  p += __shfl_xor(p, 4);
  if (e == 0) out[i] = p;
}

extern "C" void kernel_launch(void* const* d_in, const int* in_sizes, int n_in,
                              void* d_out, int out_size, void* d_ws, size_t ws_size,
                              hipStream_t stream) {
  const float* x   = (const float*)d_in[0];
  const int*   ei  = (const int*)d_in[1];
  const int*   eli = (const int*)d_in[2];
  const float* W1  = (const float*)d_in[3];
  const float* b1  = (const float*)d_in[4];
  const float* W2  = (const float*)d_in[5];
  const float* b2  = (const float*)d_in[6];
  float* logits = (float*)d_out;

  int N = in_sizes[0] / IN_CH;
  int E = in_sizes[1] / 2;
  int L = in_sizes[2] / 2;
  const int* src = ei;
  const int* dst = ei + E;
  const int* la  = eli;
  const int* lb  = eli + L;

  char* ws = (char*)d_ws;
  size_t off = 0;
  auto alloc = [&](size_t bytes) {
    void* p = ws + off;
    off = (off + bytes + 255) & ~(size_t)255;
    return p;
  };
  int*      cnt    = (int*)alloc((size_t)N * 4);
  int*      cursor = (int*)alloc((size_t)N * 4);
  int*      rowptr = (int*)alloc((size_t)(N + 1) * 4);
  float*    dinv   = (float*)alloc((size_t)N * 4);
  int*      col    = (int*)alloc((size_t)E * 4);
  unsigned short* hs  = (unsigned short*)alloc((size_t)N * HID_CH * 2);  // bf16 h*dinv
  float*    hr     = (float*)alloc((size_t)N * HID_CH * 4);              // fp32 relu out
  unsigned short* h2s = (unsigned short*)alloc((size_t)N * OUT_CH * 2);  // bf16 h2*dinv
  unsigned* zu     = (unsigned*)alloc((size_t)N * OUT_CH * 2);           // bf16 z
  int*      bsum   = (int*)alloc(256 * 4);
  int*      boff   = (int*)alloc(256 * 4);

  const int TB = 256;
  int nscan = (N + SCAN_CHUNK - 1) / SCAN_CHUNK;
  // cnt/cursor must be zero EVERY call (harness doesn't re-poison between replays);
  // custom kernel: rocclr fillBuffer was ~44 us per 160 KB memset.
  k_zero<<<(N / 4 + TB - 1) / TB, TB, 0, stream>>>(cnt, cursor, N);
  k_count<<<(E / 4 + TB - 1) / TB, TB, 0, stream>>>(dst, cnt, E);
  k_scan_part<<<nscan, 256, 0, stream>>>(cnt, bsum, dinv, N);
  k_scan_top <<<1, 256, 0, stream>>>(bsum, boff, nscan);
  k_scan_fill<<<nscan, 256, 0, stream>>>(cnt, boff, rowptr, N, E);
  k_fill <<<(E / 4 + TB - 1) / TB, TB, 0, stream>>>(src, dst, rowptr, cursor, col, E);

  // layer 1: hs = bf16((x@W1)*dinv) ; hr = relu(dn*(hs[n]+sum hs[col]) + b1)
  k_gemm<IN_CH, HID_CH><<<(N + 31) / 32, 256, 0, stream>>>(x, W1, dinv, hs, N);
  k_agg128<<<(N + 3) / 4, 256, 0, stream>>>((const unsigned*)hs, rowptr, col, dinv, b1, hr, N);

  // layer 2: h2s = bf16((hr@W2)*dinv) ; z = bf16(dn*(h2s[n]+sum h2s[col]) + b2)
  k_gemm<HID_CH, OUT_CH><<<(N + 63) / 64, 256, 0, stream>>>(hr, W2, dinv, h2s, N);
  k_agg64<<<(N + 7) / 8, 256, 0, stream>>>((const unsigned*)h2s, rowptr, col, dinv, b2, zu, N);

  // decode
  k_decode<<<((size_t)L * 8 + 255) / 256, 256, 0, stream>>>((const uint4*)zu, la, lb, logits, L);
}

// Round 6
// 135.282 us; speedup vs baseline: 2.7950x; 1.2803x over previous
//
#include <hip/hip_runtime.h>
#include <hip/hip_bf16.h>

constexpr int IN_CH  = 128;
constexpr int HID_CH = 128;
constexpr int OUT_CH = 64;
constexpr int SCAN_CHUNK = 1024;   // elements per scan block (256 thr x 4)

typedef __attribute__((ext_vector_type(8))) short bf16x8;
typedef __attribute__((ext_vector_type(4))) float f32x4;

// ---------------- bf16 pack/unpack helpers ----------------

__device__ inline unsigned short f2bf(float f) {
  __hip_bfloat16 h = __float2bfloat16(f);   // RN
  return *reinterpret_cast<unsigned short*>(&h);
}
__device__ inline unsigned pack_bf16x2(float lo, float hi) {
  return (unsigned)f2bf(lo) | ((unsigned)f2bf(hi) << 16);
}
__device__ inline float bf_lo(unsigned u) { return __uint_as_float(u << 16); }
__device__ inline float bf_hi(unsigned u) { return __uint_as_float(u & 0xffff0000u); }

// ---------------- workspace zeroing (rocclr fill replacement) ----------------

__global__ __launch_bounds__(256) void k_zero(int* __restrict__ a, int n) {
  int i = (blockIdx.x * 256 + threadIdx.x) * 4;
  if (i + 3 < n) *(int4*)&a[i] = make_int4(0, 0, 0, 0);
  else for (int j = 0; j < 4 && i + j < n; ++j) a[i + j] = 0;
}

// ---------------- CSR build ----------------
// count degree AND remember each edge's slot (ord) so k_fill needs no atomics.

__global__ void k_count(const int* __restrict__ dst, int* __restrict__ cnt,
                        int* __restrict__ ord, int E) {
  int e = (blockIdx.x * blockDim.x + threadIdx.x) * 4;
  if (e + 3 < E) {
    int4 v = *(const int4*)&dst[e];
    int4 o;
    o.x = atomicAdd(&cnt[v.x], 1);
    o.y = atomicAdd(&cnt[v.y], 1);
    o.z = atomicAdd(&cnt[v.z], 1);
    o.w = atomicAdd(&cnt[v.w], 1);
    *(int4*)&ord[e] = o;
  } else {
    for (int j = 0; j < 4 && e + j < E; ++j) ord[e + j] = atomicAdd(&cnt[dst[e + j]], 1);
  }
}

// phase 1 of scan, fused with dinv computation (both only read cnt)
__global__ __launch_bounds__(256) void k_scan_part(const int* __restrict__ cnt,
                                                   int* __restrict__ bsum,
                                                   float* __restrict__ dinv, int N) {
  int t = threadIdx.x;
  int base = blockIdx.x * SCAN_CHUNK + t * 4;
  int s = 0;
  if (base + 3 < N) {
    int4 v = *(const int4*)&cnt[base];
    s = v.x + v.y + v.z + v.w;
    float4 d;
    d.x = rsqrtf((float)v.x + 1.0f);
    d.y = rsqrtf((float)v.y + 1.0f);
    d.z = rsqrtf((float)v.z + 1.0f);
    d.w = rsqrtf((float)v.w + 1.0f);
    *(float4*)&dinv[base] = d;
  } else {
    for (int j = 0; j < 4; ++j)
      if (base + j < N) {
        int c = cnt[base + j];
        s += c;
        dinv[base + j] = rsqrtf((float)c + 1.0f);
      }
  }
  __shared__ int red[256];
  red[t] = s; __syncthreads();
  for (int off = 128; off; off >>= 1) {
    if (t < off) red[t] += red[t + off];
    __syncthreads();
  }
  if (t == 0) bsum[blockIdx.x] = red[0];
}

// phase 2+3 fused: each block derives its global offset from bsum (nblk <= 64)
__global__ __launch_bounds__(256) void k_scan_fill(const int* __restrict__ cnt,
                                                   const int* __restrict__ bsum,
                                                   int* __restrict__ rowptr, int N, int E) {
  int t = threadIdx.x;
  int boff = 0;
  for (int i = 0; i < blockIdx.x; ++i) boff += bsum[i];  // tiny: <64 scalar loads
  int base = blockIdx.x * SCAN_CHUNK + t * 4;
  int v[4] = {0, 0, 0, 0};
  if (base + 3 < N) {
    int4 q = *(const int4*)&cnt[base];
    v[0] = q.x; v[1] = q.y; v[2] = q.z; v[3] = q.w;
  } else {
    for (int j = 0; j < 4; ++j) if (base + j < N) v[j] = cnt[base + j];
  }
  int mysum = v[0] + v[1] + v[2] + v[3];
  __shared__ int s[256];
  s[t] = mysum; __syncthreads();
  for (int off = 1; off < 256; off <<= 1) {
    int add = (t >= off) ? s[t - off] : 0;
    __syncthreads();
    s[t] += add;
    __syncthreads();
  }
  int run = boff + s[t] - mysum;  // exclusive prefix for my 4
  for (int j = 0; j < 4; ++j) {
    if (base + j < N) rowptr[base + j] = run;
    run += v[j];
  }
  if (blockIdx.x == 0 && t == 0) rowptr[N] = E;
}

__global__ void k_fill(const int* __restrict__ src, const int* __restrict__ dst,
                       const int* __restrict__ ord, const int* __restrict__ rowptr,
                       int* __restrict__ col, int E) {
  int e0 = (blockIdx.x * blockDim.x + threadIdx.x) * 4;
  if (e0 >= E) return;
  if (e0 + 3 < E) {
    int4 sv = *(const int4*)&src[e0];
    int4 dv = *(const int4*)&dst[e0];
    int4 ov = *(const int4*)&ord[e0];
    col[rowptr[dv.x] + ov.x] = sv.x;
    col[rowptr[dv.y] + ov.y] = sv.y;
    col[rowptr[dv.z] + ov.z] = sv.z;
    col[rowptr[dv.w] + ov.w] = sv.w;
  } else {
    for (int j = 0; j < 4 && e0 + j < E; ++j)
      col[rowptr[dst[e0 + j]] + ord[e0 + j]] = src[e0 + j];
  }
}

// ---------------- MFMA bf16 GEMM ----------------
// Y_bf16[r][c] = bf16( (X[r,:] @ W[:,c]) * dinv[r] ),  K = 128.
// 256 thr = 4 waves; wave w owns rows [blk*64 + 16w, +16), all OUT cols.
// A-frags straight from global (fp32 or bf16); W staged once to LDS as
// Wt[col][k] bf16 with T2 XOR swizzle (byte ^= (col&7)<<4) to avoid the
// 16-way bank conflict of the 256B column stride.
// MFMA 16x16x32 lane map: A: row=l&15, k=(l>>4)*8+j ; B: col=l&15, same k;
// C/D: col=l&15, row=(l>>4)*4+reg  [m89].

template <int OUT, bool A_BF16>
__global__ __launch_bounds__(256) void k_gemm(const void* __restrict__ Xv,
                                              const float* __restrict__ W,
                                              const float* __restrict__ dinv,
                                              unsigned short* __restrict__ Y, int N) {
  constexpr int KD = 128;
  __shared__ unsigned short Wt[OUT * KD];  // [col][k] bf16, XOR-swizzled
  int t = threadIdx.x;
  for (int i = t * 4; i < KD * OUT; i += 1024) {
    int k = i / OUT, c = i % OUT;
    float4 w4 = *(const float4*)&W[i];
    float wa[4] = {w4.x, w4.y, w4.z, w4.w};
#pragma unroll
    for (int j = 0; j < 4; ++j) {
      int colj = c + j;
      int byte = colj * (KD * 2) + k * 2;
      byte ^= ((colj & 7) << 4);
      *(unsigned short*)((char*)Wt + byte) = f2bf(wa[j]);
    }
  }
  __syncthreads();

  int w = t >> 6, l = t & 63;
  int lr = l & 15, kg = (l >> 4) * 8;
  int r = blockIdx.x * 64 + w * 16 + lr;
  bool valid = r < N;

  f32x4 acc[OUT / 16];
#pragma unroll
  for (int n = 0; n < OUT / 16; ++n) acc[n] = f32x4{0.f, 0.f, 0.f, 0.f};

#pragma unroll
  for (int kb = 0; kb < KD / 32; ++kb) {
    bf16x8 a = bf16x8{0, 0, 0, 0, 0, 0, 0, 0};
    if (valid) {
      if (A_BF16) {
        a = *(const bf16x8*)((const unsigned short*)Xv + (size_t)r * KD + kb * 32 + kg);
      } else {
        const float* xrow = (const float*)Xv + (size_t)r * KD + kb * 32 + kg;
        float4 x0 = *(const float4*)xrow;
        float4 x1 = *(const float4*)(xrow + 4);
        a[0] = (short)f2bf(x0.x); a[1] = (short)f2bf(x0.y);
        a[2] = (short)f2bf(x0.z); a[3] = (short)f2bf(x0.w);
        a[4] = (short)f2bf(x1.x); a[5] = (short)f2bf(x1.y);
        a[6] = (short)f2bf(x1.z); a[7] = (short)f2bf(x1.w);
      }
    }
#pragma unroll
    for (int n = 0; n < OUT / 16; ++n) {
      int col = n * 16 + lr;
      int byte = col * (KD * 2) + (kb * 32 + kg) * 2;
      byte ^= ((col & 7) << 4);
      bf16x8 b = *(const bf16x8*)((const char*)Wt + byte);
      acc[n] = __builtin_amdgcn_mfma_f32_16x16x32_bf16(a, b, acc[n], 0, 0, 0);
    }
  }

  // epilogue: scale rows by dinv, pack bf16. C row = (l>>4)*4 + reg.
  int orow = blockIdx.x * 64 + w * 16 + (l >> 4) * 4;
  float dn[4];
#pragma unroll
  for (int i = 0; i < 4; ++i) dn[i] = (orow + i < N) ? dinv[orow + i] : 0.f;
#pragma unroll
  for (int i = 0; i < 4; ++i) {
    if (orow + i >= N) continue;
#pragma unroll
    for (int n = 0; n < OUT / 16; ++n)
      Y[(size_t)(orow + i) * OUT + n * 16 + lr] = f2bf(acc[n][i] * dn[i]);
  }
}

// ---------------- aggregation, 128ch bf16 table -> bf16 out (relu) ----------------
// One wave per node; lane l owns channels 2l,2l+1; one 256B gather per edge.

__global__ __launch_bounds__(256) void k_agg128(const unsigned* __restrict__ HS,
                                                const int* __restrict__ rowptr,
                                                const int* __restrict__ col,
                                                const float* __restrict__ dinv,
                                                const float* __restrict__ bias,
                                                unsigned* __restrict__ Outb, int N) {
  int n = blockIdx.x * 4 + (threadIdx.x >> 6);
  if (n >= N) return;
  int l = threadIdx.x & 63;
  float dn = dinv[n];
  unsigned u0 = HS[(size_t)n * 64 + l];
  float ax = bf_lo(u0), ay = bf_hi(u0);
  int p = rowptr[n], pend = rowptr[n + 1];
  for (; p + 8 <= pend; p += 8) {
    int s[8]; unsigned g[8];
#pragma unroll
    for (int j = 0; j < 8; ++j) s[j] = col[p + j];
#pragma unroll
    for (int j = 0; j < 8; ++j) g[j] = HS[(size_t)s[j] * 64 + l];
#pragma unroll
    for (int j = 0; j < 8; ++j) { ax += bf_lo(g[j]); ay += bf_hi(g[j]); }
  }
  for (; p < pend; ++p) {
    unsigned g = HS[(size_t)col[p] * 64 + l];
    ax += bf_lo(g); ay += bf_hi(g);
  }
  float2 b2 = ((const float2*)bias)[l];
  Outb[(size_t)n * 64 + l] =
      pack_bf16x2(fmaxf(dn * ax + b2.x, 0.f), fmaxf(dn * ay + b2.y, 0.f));
}

// ---------------- aggregation, 64ch bf16 table -> bf16 out (no relu) ----------------

__global__ __launch_bounds__(256) void k_agg64(const unsigned* __restrict__ HS,
                                               const int* __restrict__ rowptr,
                                               const int* __restrict__ col,
                                               const float* __restrict__ dinv,
                                               const float* __restrict__ bias,
                                               unsigned* __restrict__ Zu, int N) {
  int n = blockIdx.x * 8 + (threadIdx.x >> 5);
  if (n >= N) return;
  int g = threadIdx.x & 31;
  float dn = dinv[n];
  unsigned u0 = HS[(size_t)n * 32 + g];
  float ax = bf_lo(u0), ay = bf_hi(u0);
  int p = rowptr[n], pend = rowptr[n + 1];
  for (; p + 8 <= pend; p += 8) {
    int s[8]; unsigned q[8];
#pragma unroll
    for (int j = 0; j < 8; ++j) s[j] = col[p + j];
#pragma unroll
    for (int j = 0; j < 8; ++j) q[j] = HS[(size_t)s[j] * 32 + g];
#pragma unroll
    for (int j = 0; j < 8; ++j) { ax += bf_lo(q[j]); ay += bf_hi(q[j]); }
  }
  for (; p < pend; ++p) {
    unsigned q = HS[(size_t)col[p] * 32 + g];
    ax += bf_lo(q); ay += bf_hi(q);
  }
  float2 b2 = ((const float2*)bias)[g];
  Zu[(size_t)n * 32 + g] = pack_bf16x2(dn * ax + b2.x, dn * ay + b2.y);
}

// ---------------- decode: logits[i] = dot(z[a[i]], z[b[i]]), z bf16 ----------------

__global__ __launch_bounds__(256) void k_decode(const uint4* __restrict__ Z,
                                                const int* __restrict__ ia,
                                                const int* __restrict__ ib,
                                                float* __restrict__ out, int L) {
  int t = blockIdx.x * 256 + threadIdx.x;
  int i = t >> 3;
  if (i >= L) return;
  int e = t & 7;
  int a = ia[i], b = ib[i];
  uint4 za = Z[(size_t)a * 8 + e];
  uint4 zb = Z[(size_t)b * 8 + e];
  float p = bf_lo(za.x) * bf_lo(zb.x) + bf_hi(za.x) * bf_hi(zb.x)
          + bf_lo(za.y) * bf_lo(zb.y) + bf_hi(za.y) * bf_hi(zb.y)
          + bf_lo(za.z) * bf_lo(zb.z) + bf_hi(za.z) * bf_hi(zb.z)
          + bf_lo(za.w) * bf_lo(zb.w) + bf_hi(za.w) * bf_hi(zb.w);
  p += __shfl_xor(p, 1);
  p += __shfl_xor(p, 2);
  p += __shfl_xor(p, 4);
  if (e == 0) out[i] = p;
}

extern "C" void kernel_launch(void* const* d_in, const int* in_sizes, int n_in,
                              void* d_out, int out_size, void* d_ws, size_t ws_size,
                              hipStream_t stream) {
  const float* x   = (const float*)d_in[0];
  const int*   ei  = (const int*)d_in[1];
  const int*   eli = (const int*)d_in[2];
  const float* W1  = (const float*)d_in[3];
  const float* b1  = (const float*)d_in[4];
  const float* W2  = (const float*)d_in[5];
  const float* b2  = (const float*)d_in[6];
  float* logits = (float*)d_out;

  int N = in_sizes[0] / IN_CH;
  int E = in_sizes[1] / 2;
  int L = in_sizes[2] / 2;
  const int* src = ei;
  const int* dst = ei + E;
  const int* la  = eli;
  const int* lb  = eli + L;

  char* ws = (char*)d_ws;
  size_t off = 0;
  auto alloc = [&](size_t bytes) {
    void* p = ws + off;
    off = (off + bytes + 255) & ~(size_t)255;
    return p;
  };
  int*      cnt    = (int*)alloc((size_t)N * 4);
  int*      rowptr = (int*)alloc((size_t)(N + 1) * 4);
  float*    dinv   = (float*)alloc((size_t)N * 4);
  int*      col    = (int*)alloc((size_t)E * 4);
  int*      ord    = (int*)alloc((size_t)E * 4);
  unsigned short* hs  = (unsigned short*)alloc((size_t)N * HID_CH * 2);  // bf16 h*dinv
  unsigned* hrb    = (unsigned*)alloc((size_t)N * HID_CH * 2);           // bf16 relu out
  unsigned short* h2s = (unsigned short*)alloc((size_t)N * OUT_CH * 2);  // bf16 h2*dinv
  unsigned* zu     = (unsigned*)alloc((size_t)N * OUT_CH * 2);           // bf16 z
  int*      bsum   = (int*)alloc(256 * 4);

  const int TB = 256;
  int nscan = (N + SCAN_CHUNK - 1) / SCAN_CHUNK;
  // cnt must be zero EVERY call (harness doesn't re-poison between replays)
  k_zero<<<(N / 4 + TB - 1) / TB, TB, 0, stream>>>(cnt, N);
  k_count<<<(E / 4 + TB - 1) / TB, TB, 0, stream>>>(dst, cnt, ord, E);
  k_scan_part<<<nscan, 256, 0, stream>>>(cnt, bsum, dinv, N);
  k_scan_fill<<<nscan, 256, 0, stream>>>(cnt, bsum, rowptr, N, E);
  k_fill <<<(E / 4 + TB - 1) / TB, TB, 0, stream>>>(src, dst, ord, rowptr, col, E);

  // layer 1: hs = bf16((x@W1)*dinv) ; hrb = bf16(relu(dn*(hs[n]+sum hs[col]) + b1))
  k_gemm<HID_CH, false><<<(N + 63) / 64, 256, 0, stream>>>(x, W1, dinv, hs, N);
  k_agg128<<<(N + 3) / 4, 256, 0, stream>>>((const unsigned*)hs, rowptr, col, dinv, b1, hrb, N);

  // layer 2: h2s = bf16((hrb@W2)*dinv) ; z = bf16(dn*(h2s[n]+sum h2s[col]) + b2)
  k_gemm<OUT_CH, true><<<(N + 63) / 64, 256, 0, stream>>>(hrb, W2, dinv, h2s, N);
  k_agg64<<<(N + 7) / 8, 256, 0, stream>>>((const unsigned*)h2s, rowptr, col, dinv, b2, zu, N);

  // decode
  k_decode<<<((size_t)L * 8 + 255) / 256, 256, 0, stream>>>((const uint4*)zu, la, lb, logits, L);
}